// Round 1
// baseline (2638.037 us; speedup 1.0000x reference)
//
#include <hip/hip_runtime.h>
#include <stdint.h>

#define HH 80
#define WW 80
#define CC 64
#define BB 32
#define NDIAG (HH + WW - 1)  // 159

typedef _Float16 f16;
typedef _Float16 f16x8 __attribute__((ext_vector_type(8)));
typedef _Float16 f16x4 __attribute__((ext_vector_type(4)));
typedef float floatx4 __attribute__((ext_vector_type(4)));

struct GPtrs { const float* p[8]; };

// ---------------------------------------------------------------------------
// Pre-pass: x[b][c][i][j] (f32) -> xT[((b*H+i)*W+j)*C + c] (f16)
// so the main kernel's per-cell x loads are contiguous in c (8B/lane).
// ---------------------------------------------------------------------------
__global__ __launch_bounds__(256) void xpose_kernel(const float* __restrict__ x,
                                                    f16* __restrict__ xT) {
  const int bi = blockIdx.x;            // 0 .. B*H-1
  const int b = bi / HH;
  const int i = bi - b * HH;
  __shared__ f16 tile[CC][WW + 1];      // +1 pad breaks bank conflicts on transpose read
  const float* xp = x + ((size_t)(b * CC) * HH + i) * WW;  // + c*(H*W) + j
  for (int idx = threadIdx.x; idx < CC * WW; idx += 256) {
    const int c = idx / WW;
    const int j = idx - c * WW;         // consecutive idx -> consecutive j (coalesced)
    tile[c][j] = (f16)xp[(size_t)c * (HH * WW) + j];
  }
  __syncthreads();
  f16* op = xT + (size_t)(b * HH + i) * WW * CC;
  for (int idx = threadIdx.x; idx < WW * CC; idx += 256) {
    const int j = idx >> 6;
    const int c = idx & (CC - 1);       // consecutive idx -> consecutive c (coalesced)
    op[idx] = tile[c][j];
  }
}

// ---------------------------------------------------------------------------
// Main kernel: one block per (direction, batch) = 128 blocks, 256 threads.
// Anti-diagonal wavefront in flipped coordinates; per diagonal the two
// neighbor contributions are GEMMs [64,64]@[64,n_d] done with
// v_mfma_f32_16x16x32_f16. Gamma A-fragments are loop-invariant -> registers.
// Diagonal h state double-buffered in LDS (f16, padded rows, guard rows).
// ---------------------------------------------------------------------------
__global__ __launch_bounds__(256) void dag_kernel(const f16* __restrict__ xT,
                                                  GPtrs g,
                                                  float* __restrict__ out) {
  const int blk = blockIdx.x;   // 0..127
  const int dir = blk >> 5;     // 0:SE 1:NE 2:NW 3:SW
  const int b   = blk & 31;
  const int tid = threadIdx.x;
  const int wave = tid >> 6;    // 0..3 -> fixed comp-tile (rows wave*16..wave*16+15)
  const int lane = tid & 63;
  const int l15  = lane & 15;
  const int quad = lane >> 4;

  const bool fi      = (dir == 1) || (dir == 2);  // flip i
  const bool fj      = (dir == 2) || (dir == 3);  // flip j
  const bool do_relu = (dir != 3);                // SW scan has no ReLU
  const float* __restrict__ gv = g.p[2 * dir];
  const float* __restrict__ gh = g.p[2 * dir + 1];

  // [parity][s][c]: s = i'+1; s=0 is the i'=-1 zero guard, s=81 the top guard.
  // Row stride 72 f16 = 144 B (16B-aligned, 36-bank stride -> conflict-light b128).
  __shared__ f16 hbuf[2][HH + 2][CC + 8];
  {
    f16* hz = &hbuf[0][0][0];
    const int tot = 2 * (HH + 2) * (CC + 8);
    for (int idx = tid; idx < tot; idx += 256) hz[idx] = (f16)0.0f;
  }

  // A fragments (gamma rows for this wave's 16 output comps), kept in VGPRs.
  // A[m][k]: m = lane&15, k = quad*8 + j  (16x16x32 f16 layout).
  f16x8 Av0, Av1, Ah0, Ah1;
  {
    const int row = wave * 16 + l15;
    const float* pv = gv + row * CC;
    const float* ph = gh + row * CC;
    f16x8 av0, av1, ah0, ah1;
#pragma unroll
    for (int jj = 0; jj < 8; ++jj) {
      av0[jj] = (f16)pv[quad * 8 + jj];
      av1[jj] = (f16)pv[32 + quad * 8 + jj];
      ah0[jj] = (f16)ph[quad * 8 + jj];
      ah1[jj] = (f16)ph[32 + quad * 8 + jj];
    }
    Av0 = av0; Av1 = av1; Ah0 = ah0; Ah1 = ah1;
  }
  const int c0 = wave * 16 + quad * 4;  // this lane's 4 output comps (C/D layout)

  __syncthreads();

  for (int d = 0; d < NDIAG; ++d) {
    const int p = d & 1;       // current parity
    const int q = p ^ 1;       // previous parity
    const int ilo = max(0, d - (WW - 1));
    const int ihi = min(d, HH - 1);
    const int nd = ihi - ilo + 1;
    const int ntiles = (nd + 15) >> 4;

    for (int clt = 0; clt < ntiles; ++clt) {
      const int cb  = ilo + clt * 16;
      const int ip  = cb + l15;          // this lane's column cell row i'
      const int ipc = min(ip, ihi);      // clamped (address safety for masked lanes)
      // neighbor storage rows (clamped into guard): up=(i'-1,j') -> s=i'; left=(i',j'-1) -> s=i'+1
      const int su = min(ip, HH + 1);
      const int sl = min(ip + 1, HH + 1);

      // x load (independent of LDS deps; issued early)
      const int jp = d - ipc;
      const int io = fi ? (HH - 1 - ipc) : ipc;
      const int jo = fj ? (WW - 1 - jp) : jp;
      const f16x4 xv = *(const f16x4*)(xT + ((size_t)(b * HH + io) * WW + jo) * CC + c0);

      // B fragments: B[k][n]: n = lane&15 (cell), k = quad*8 + j
      const f16x8 bu0 = *(const f16x8*)&hbuf[q][su][quad * 8];
      const f16x8 bu1 = *(const f16x8*)&hbuf[q][su][32 + quad * 8];
      const f16x8 bl0 = *(const f16x8*)&hbuf[q][sl][quad * 8];
      const f16x8 bl1 = *(const f16x8*)&hbuf[q][sl][32 + quad * 8];

      floatx4 acc = {0.f, 0.f, 0.f, 0.f};
      acc = __builtin_amdgcn_mfma_f32_16x16x32_f16(Av0, bu0, acc, 0, 0, 0);
      acc = __builtin_amdgcn_mfma_f32_16x16x32_f16(Av1, bu1, acc, 0, 0, 0);
      acc = __builtin_amdgcn_mfma_f32_16x16x32_f16(Ah0, bl0, acc, 0, 0, 0);
      acc = __builtin_amdgcn_mfma_f32_16x16x32_f16(Ah1, bl1, acc, 0, 0, 0);

      if (ip <= ihi) {
        float h0 = acc[0] + (float)xv[0];
        float h1 = acc[1] + (float)xv[1];
        float h2 = acc[2] + (float)xv[2];
        float h3 = acc[3] + (float)xv[3];
        if (do_relu) {
          h0 = fmaxf(h0, 0.f); h1 = fmaxf(h1, 0.f);
          h2 = fmaxf(h2, 0.f); h3 = fmaxf(h3, 0.f);
        }
        f16x4 hw;
        hw[0] = (f16)h0; hw[1] = (f16)h1; hw[2] = (f16)h2; hw[3] = (f16)h3;
        *(f16x4*)&hbuf[p][ip + 1][c0] = hw;

        float* po = out + ((size_t)(b * CC + c0) * HH + io) * WW + jo;
        atomicAdd(po,                 h0);
        atomicAdd(po +     HH * WW,   h1);
        atomicAdd(po + 2 * HH * WW,   h2);
        atomicAdd(po + 3 * HH * WW,   h3);
      }
    }
    __syncthreads();
  }
}

// ---------------------------------------------------------------------------
extern "C" void kernel_launch(void* const* d_in, const int* in_sizes, int n_in,
                              void* d_out, int out_size, void* d_ws, size_t ws_size,
                              hipStream_t stream) {
  const float* x = (const float*)d_in[0];
  GPtrs g;
  for (int k = 0; k < 8; ++k) g.p[k] = (const float*)d_in[k + 1];  // g1,g2,g4,g5,g7,g8,g10,g11
  f16* xT = (f16*)d_ws;  // needs B*H*W*C*2 = 26.2 MB of workspace

  hipMemsetAsync(d_out, 0, (size_t)out_size * sizeof(float), stream);
  xpose_kernel<<<BB * HH, 256, 0, stream>>>(x, xT);
  dag_kernel<<<4 * BB, 256, 0, stream>>>((const f16*)xT, g, (float*)d_out);
}

// Round 2
// 396.470 us; speedup vs baseline: 6.6538x; 6.6538x over previous
//
#include <hip/hip_runtime.h>
#include <stdint.h>

#define HH 80
#define WW 80
#define CC 64
#define BB 32
#define NDIAG (HH + WW - 1)  // 159

typedef _Float16 f16;
typedef _Float16 f16x8 __attribute__((ext_vector_type(8)));
typedef _Float16 f16x4 __attribute__((ext_vector_type(4)));
typedef float floatx4 __attribute__((ext_vector_type(4)));

struct GPtrs { const float* p[8]; };

// ---------------------------------------------------------------------------
// Pre-pass: x[b][c][i][j] (f32) -> xT[((b*H+i)*W+j)*C + c] (f16)
// ---------------------------------------------------------------------------
__global__ __launch_bounds__(256) void xpose_kernel(const float* __restrict__ x,
                                                    f16* __restrict__ xT) {
  const int bi = blockIdx.x;            // 0 .. B*H-1
  const int b = bi / HH;
  const int i = bi - b * HH;
  __shared__ f16 tile[CC][WW + 1];      // +1 pad breaks bank conflicts
  const float* xp = x + ((size_t)(b * CC) * HH + i) * WW;  // + c*(H*W) + j
  for (int idx = threadIdx.x; idx < CC * WW; idx += 256) {
    const int c = idx / WW;
    const int j = idx - c * WW;         // consecutive idx -> consecutive j (coalesced)
    tile[c][j] = (f16)xp[(size_t)c * (HH * WW) + j];
  }
  __syncthreads();
  f16* op = xT + (size_t)(b * HH + i) * WW * CC;
  for (int idx = threadIdx.x; idx < WW * CC; idx += 256) {
    const int j = idx >> 6;
    const int c = idx & (CC - 1);       // consecutive idx -> consecutive c (coalesced)
    op[idx] = tile[c][j];
  }
}

// ---------------------------------------------------------------------------
// Main kernel: one block per (direction, batch) = 128 blocks, 256 threads.
// Anti-diagonal wavefront; per diagonal two GEMMs [64,64]@[64,n_d] via
// v_mfma_f32_16x16x32_f16. Gamma A-fragments live in VGPRs. Diagonal h state
// double-buffered in LDS. Output h -> private f16 scratch (NO atomics):
// scratch[dir][b][io][jo][c], plain f16x4 stores (32B contiguous/wave/cell).
// ---------------------------------------------------------------------------
__global__ __launch_bounds__(256) void dag_kernel(const f16* __restrict__ xT,
                                                  GPtrs g,
                                                  f16* __restrict__ scratch) {
  const int blk = blockIdx.x;   // 0..127
  const int dir = blk >> 5;     // 0:SE 1:NE 2:NW 3:SW
  const int b   = blk & 31;
  const int tid = threadIdx.x;
  const int wave = tid >> 6;    // 0..3 -> this wave's 16 output channels
  const int lane = tid & 63;
  const int l15  = lane & 15;
  const int quad = lane >> 4;

  const bool fi      = (dir == 1) || (dir == 2);  // flip i
  const bool fj      = (dir == 2) || (dir == 3);  // flip j
  const bool do_relu = (dir != 3);                // SW scan has no ReLU
  const float* __restrict__ gv = g.p[2 * dir];
  const float* __restrict__ gh = g.p[2 * dir + 1];

  // [parity][s][c]: s = i'+1; s=0 is the i'=-1 zero guard, s=81 the top guard.
  __shared__ f16 hbuf[2][HH + 2][CC + 8];
  {
    f16* hz = &hbuf[0][0][0];
    const int tot = 2 * (HH + 2) * (CC + 8);
    for (int idx = tid; idx < tot; idx += 256) hz[idx] = (f16)0.0f;
  }

  // A fragments: A[m][k], m = lane&15, k = quad*8 + j (16x16x32 f16 layout).
  f16x8 Av0, Av1, Ah0, Ah1;
  {
    const int row = wave * 16 + l15;
    const float* pv = gv + row * CC;
    const float* ph = gh + row * CC;
    f16x8 av0, av1, ah0, ah1;
#pragma unroll
    for (int jj = 0; jj < 8; ++jj) {
      av0[jj] = (f16)pv[quad * 8 + jj];
      av1[jj] = (f16)pv[32 + quad * 8 + jj];
      ah0[jj] = (f16)ph[quad * 8 + jj];
      ah1[jj] = (f16)ph[32 + quad * 8 + jj];
    }
    Av0 = av0; Av1 = av1; Ah0 = ah0; Ah1 = ah1;
  }
  const int c0 = wave * 16 + quad * 4;  // this lane's 4 output channels (C/D layout)

  f16* const sbase = scratch + (size_t)(dir * BB + b) * (HH * WW) * CC;

  __syncthreads();

  for (int d = 0; d < NDIAG; ++d) {
    const int p = d & 1;       // current parity
    const int q = p ^ 1;       // previous parity
    const int ilo = max(0, d - (WW - 1));
    const int ihi = min(d, HH - 1);
    const int nd = ihi - ilo + 1;
    const int ntiles = (nd + 15) >> 4;

    for (int clt = 0; clt < ntiles; ++clt) {
      const int cb  = ilo + clt * 16;
      const int ip  = cb + l15;          // this lane's cell row i'
      const int ipc = min(ip, ihi);      // clamped (address safety for masked lanes)
      const int su = min(ip, HH + 1);    // up neighbor row (i'-1,j') -> s=i'
      const int sl = min(ip + 1, HH + 1);// left neighbor row (i',j'-1) -> s=i'+1

      // x load (independent of LDS deps; issued early)
      const int jp = d - ipc;
      const int io = fi ? (HH - 1 - ipc) : ipc;
      const int jo = fj ? (WW - 1 - jp) : jp;
      const f16x4 xv = *(const f16x4*)(xT + ((size_t)(b * HH + io) * WW + jo) * CC + c0);

      // B fragments: B[k][n], n = lane&15 (cell), k = quad*8 + j
      const f16x8 bu0 = *(const f16x8*)&hbuf[q][su][quad * 8];
      const f16x8 bu1 = *(const f16x8*)&hbuf[q][su][32 + quad * 8];
      const f16x8 bl0 = *(const f16x8*)&hbuf[q][sl][quad * 8];
      const f16x8 bl1 = *(const f16x8*)&hbuf[q][sl][32 + quad * 8];

      floatx4 acc = {0.f, 0.f, 0.f, 0.f};
      acc = __builtin_amdgcn_mfma_f32_16x16x32_f16(Av0, bu0, acc, 0, 0, 0);
      acc = __builtin_amdgcn_mfma_f32_16x16x32_f16(Av1, bu1, acc, 0, 0, 0);
      acc = __builtin_amdgcn_mfma_f32_16x16x32_f16(Ah0, bl0, acc, 0, 0, 0);
      acc = __builtin_amdgcn_mfma_f32_16x16x32_f16(Ah1, bl1, acc, 0, 0, 0);

      if (ip <= ihi) {
        float h0 = acc[0] + (float)xv[0];
        float h1 = acc[1] + (float)xv[1];
        float h2 = acc[2] + (float)xv[2];
        float h3 = acc[3] + (float)xv[3];
        if (do_relu) {
          h0 = fmaxf(h0, 0.f); h1 = fmaxf(h1, 0.f);
          h2 = fmaxf(h2, 0.f); h3 = fmaxf(h3, 0.f);
        }
        f16x4 hw;
        hw[0] = (f16)h0; hw[1] = (f16)h1; hw[2] = (f16)h2; hw[3] = (f16)h3;
        *(f16x4*)&hbuf[p][ip + 1][c0] = hw;
        // private scratch store: no atomics, 8B/lane, 32B contiguous per wave/cell
        *(f16x4*)(sbase + ((size_t)io * WW + jo) * CC + c0) = hw;
      }
    }
    __syncthreads();
  }
}

// ---------------------------------------------------------------------------
// Reduce: out[b][c][i][j] = sum over 4 dirs of scratch[dir][b][i][j][c],
// fp32 accumulate, LDS transpose for coalesced [B,C,H,W] stores.
// One block per (b, i) = 2560 blocks.
// ---------------------------------------------------------------------------
__global__ __launch_bounds__(256) void reduce_kernel(const f16* __restrict__ s,
                                                     float* __restrict__ out) {
  const int bi = blockIdx.x;            // b*HH + i
  const int b = bi / HH;
  const int i = bi - b * HH;
  __shared__ float tile[CC][WW + 1];
  const size_t dstride = (size_t)BB * HH * WW * CC;
  const f16* p = s + ((size_t)b * HH + i) * WW * CC;
  for (int idx = threadIdx.x; idx < (WW * CC) / 4; idx += 256) {  // 1280 f16x4 chunks
    const int j  = idx >> 4;
    const int c4 = (idx & 15) * 4;
    const size_t off = (size_t)j * CC + c4;
    const f16x4 a0 = *(const f16x4*)(p + off);
    const f16x4 a1 = *(const f16x4*)(p + off + dstride);
    const f16x4 a2 = *(const f16x4*)(p + off + 2 * dstride);
    const f16x4 a3 = *(const f16x4*)(p + off + 3 * dstride);
#pragma unroll
    for (int k = 0; k < 4; ++k)
      tile[c4 + k][j] = (float)a0[k] + (float)a1[k] + (float)a2[k] + (float)a3[k];
  }
  __syncthreads();
  float* op = out + ((size_t)b * CC * HH + i) * WW;  // + c*(H*W) + j
  for (int idx = threadIdx.x; idx < CC * WW; idx += 256) {
    const int c = idx / WW;
    const int j = idx - c * WW;         // consecutive idx -> consecutive j (coalesced)
    op[(size_t)c * (HH * WW) + j] = tile[c][j];
  }
}

// ---------------------------------------------------------------------------
extern "C" void kernel_launch(void* const* d_in, const int* in_sizes, int n_in,
                              void* d_out, int out_size, void* d_ws, size_t ws_size,
                              hipStream_t stream) {
  const float* x = (const float*)d_in[0];
  GPtrs g;
  for (int k = 0; k < 8; ++k) g.p[k] = (const float*)d_in[k + 1];  // g1,g2,g4,g5,g7,g8,g10,g11
  f16* xT = (f16*)d_ws;                                   // 26.2 MB
  f16* scratch = (f16*)((char*)d_ws + (size_t)BB * HH * WW * CC * sizeof(f16));  // 104.9 MB

  xpose_kernel<<<BB * HH, 256, 0, stream>>>(x, xT);
  dag_kernel<<<4 * BB, 256, 0, stream>>>((const f16*)xT, g, scratch);
  reduce_kernel<<<BB * HH, 256, 0, stream>>>((const f16*)scratch, (float*)d_out);
}

// Round 3
// 326.542 us; speedup vs baseline: 8.0787x; 1.2141x over previous
//
#include <hip/hip_runtime.h>
#include <stdint.h>

#define HH 80
#define WW 80
#define CC 64
#define BB 32
#define NDIAG (HH + WW - 1)   // 159
#define SLICE (HH * WW * CC)  // 409600 f16 per (dir,b) scratch slice

typedef _Float16 f16;
typedef _Float16 f16x8 __attribute__((ext_vector_type(8)));
typedef _Float16 f16x4 __attribute__((ext_vector_type(4)));
typedef float floatx4 __attribute__((ext_vector_type(4)));

struct GPtrs { const float* p[8]; };

// ---------------------------------------------------------------------------
// Pre-pass: x[b][c][i][j] (f32) -> xT[((b*H+i)*W+j)*C + c] (f16).
// LDS tile [j][c] (stride 68 -> 16B-aligned rows), float4 LDS reads,
// f16x4 vectorized global stores (128B contiguous per 16 lanes).
// ---------------------------------------------------------------------------
__global__ __launch_bounds__(256) void xpose_kernel(const float* __restrict__ x,
                                                    f16* __restrict__ xT) {
  const int bi = blockIdx.x;            // b*HH + i
  const int b = bi / HH, i = bi - b * HH;
  __shared__ float tile[WW][CC + 4];    // [j][c]
  const float* xp = x + ((size_t)(b * CC) * HH + i) * WW;  // + c*(H*W) + j
  for (int idx = threadIdx.x; idx < CC * WW; idx += 256) {
    const int c = idx / WW, j = idx - c * WW;   // consecutive j -> coalesced reads
    tile[j][c] = xp[(size_t)c * (HH * WW) + j];
  }
  __syncthreads();
  f16* op = xT + (size_t)(b * HH + i) * WW * CC;
  for (int idx = threadIdx.x; idx < (WW * CC) / 4; idx += 256) {
    const int j = idx >> 4, m = idx & 15;       // c4 = 4m; 16 lanes cover one j
    const floatx4 v4 = *(const floatx4*)&tile[j][m * 4];  // aligned (272j+16m)
    f16x4 v;
    v[0] = (f16)v4[0]; v[1] = (f16)v4[1]; v[2] = (f16)v4[2]; v[3] = (f16)v4[3];
    *(f16x4*)(op + j * CC + m * 4) = v;         // 128B contiguous per 16 lanes
  }
}

// ---------------------------------------------------------------------------
// Main kernel: one block per (direction, batch) = 128 blocks, 256 threads.
// Barrier-to-barrier path contains ONLY: ds_read -> MFMA -> VALU -> ds_write.
// x is register-prefetched one diagonal ahead (fixed 5 tiles, clamped);
// scratch stores are deferred one diagonal (carried in regs, flushed at the
// top of the next diagonal) so their ack is hidden behind compute before the
// compiler's vmcnt(0) barrier drain. Tile loop fully unrolled per ntiles.
// ---------------------------------------------------------------------------
__global__ __launch_bounds__(256, 1) void dag_kernel(const f16* __restrict__ xT,
                                                     GPtrs g,
                                                     f16* __restrict__ scratch) {
  const int blk = blockIdx.x;   // 0..127
  const int dir = blk >> 5;     // 0:SE 1:NE 2:NW 3:SW
  const int b   = blk & 31;
  const int tid = threadIdx.x;
  const int wave = tid >> 6;    // this wave's 16 output channels
  const int lane = tid & 63;
  const int l15  = lane & 15;
  const int quad = lane >> 4;

  const bool fi      = (dir == 1) || (dir == 2);  // flip i
  const bool fj      = (dir == 2) || (dir == 3);  // flip j
  const bool do_relu = (dir != 3);                // SW scan has no ReLU
  const float* __restrict__ gv = g.p[2 * dir];
  const float* __restrict__ gh = g.p[2 * dir + 1];

  // [parity][s][c]: s = i'+1; s=0 is the i'=-1 zero guard, s=81 the top guard.
  __shared__ f16 hbuf[2][HH + 2][CC + 8];
  for (int idx = tid; idx < 2 * (HH + 2) * (CC + 8); idx += 256)
    (&hbuf[0][0][0])[idx] = (f16)0.0f;

  // A fragments: A[m][k], m = lane&15, k = quad*8 + j (16x16x32 f16 layout).
  f16x8 Av0, Av1, Ah0, Ah1;
  {
    const int row = wave * 16 + l15;
    const float* pv = gv + row * CC;
    const float* ph = gh + row * CC;
#pragma unroll
    for (int jj = 0; jj < 8; ++jj) {
      Av0[jj] = (f16)pv[quad * 8 + jj];
      Av1[jj] = (f16)pv[32 + quad * 8 + jj];
      Ah0[jj] = (f16)ph[quad * 8 + jj];
      Ah1[jj] = (f16)ph[32 + quad * 8 + jj];
    }
  }
  const int c0 = wave * 16 + quad * 4;  // this lane's 4 output channels (C/D layout)
  const f16* const xTb = xT + (size_t)b * SLICE;
  f16* const sbase = scratch + (size_t)blk * SLICE;

  // Fixed-5-tile x prefetch for diagonal d1 (clamped addresses for dead lanes).
  auto prefetch = [&](int d1, f16x4* xv, int* offv) {
    const int ilo1 = max(0, d1 - (WW - 1));
    const int ihi1 = min(d1, HH - 1);
#pragma unroll
    for (int t = 0; t < 5; ++t) {
      const int ip1 = min(ilo1 + t * 16 + l15, ihi1);
      const int jp1 = d1 - ip1;                       // in [0,79] by construction
      const int io1 = fi ? (HH - 1 - ip1) : ip1;
      const int jo1 = fj ? (WW - 1 - jp1) : jp1;
      const int off = ((io1 * WW + jo1) << 6) + c0;   // cell offset in xT/scratch
      offv[t] = off;
      xv[t] = *(const f16x4*)(xTb + off);
    }
  };

  f16x4 xv[5]; int offv[5];
  int psoff[5]; f16x4 phw[5];   // deferred-store state (offset <0 => dead)
#pragma unroll
  for (int t = 0; t < 5; ++t) psoff[t] = -1;
  prefetch(0, xv, offv);

  __syncthreads();

  for (int d = 0; d < NDIAG; ++d) {
    const int p = d & 1, q = p ^ 1;
    const int ilo = max(0, d - (WW - 1));
    const int ihi = min(d, HH - 1);
    const int ntiles = ((ihi - ilo) >> 4) + 1;

    // 1. flush previous diagonal's stores (issue early; ack hidden by compute)
#pragma unroll
    for (int t = 0; t < 5; ++t)
      if (psoff[t] >= 0) *(f16x4*)(sbase + psoff[t]) = phw[t];

    // 2. prefetch x for next diagonal (issue early; consumed next iteration)
    f16x4 nxv[5]; int noffv[5];
    prefetch(d + 1 < NDIAG ? d + 1 : NDIAG - 1, nxv, noffv);

    const f16 (* __restrict__ hq)[CC + 8] = hbuf[q];
    f16 (* __restrict__ hp)[CC + 8] = hbuf[p];

    // 3+4. LDS reads + MFMAs + epilogue, fully unrolled per tile count.
#define DIAG_BODY(NT)                                                          \
    {                                                                          \
      f16x8 bu0[NT], bu1[NT], bl0[NT], bl1[NT];                                \
      _Pragma("unroll")                                                        \
      for (int t = 0; t < NT; ++t) {                                           \
        const int ip = ilo + t * 16 + l15;                                     \
        const int su = min(ip, HH + 1);      /* up   (i'-1,j') -> s=i'   */    \
        const int sl = min(ip + 1, HH + 1);  /* left (i',j'-1) -> s=i'+1 */    \
        bu0[t] = *(const f16x8*)&hq[su][quad * 8];                             \
        bu1[t] = *(const f16x8*)&hq[su][32 + quad * 8];                        \
        bl0[t] = *(const f16x8*)&hq[sl][quad * 8];                             \
        bl1[t] = *(const f16x8*)&hq[sl][32 + quad * 8];                        \
      }                                                                        \
      _Pragma("unroll")                                                        \
      for (int t = 0; t < NT; ++t) {                                           \
        floatx4 a = {0.f, 0.f, 0.f, 0.f};                                      \
        a = __builtin_amdgcn_mfma_f32_16x16x32_f16(Av0, bu0[t], a, 0, 0, 0);   \
        a = __builtin_amdgcn_mfma_f32_16x16x32_f16(Av1, bu1[t], a, 0, 0, 0);   \
        a = __builtin_amdgcn_mfma_f32_16x16x32_f16(Ah0, bl0[t], a, 0, 0, 0);   \
        a = __builtin_amdgcn_mfma_f32_16x16x32_f16(Ah1, bl1[t], a, 0, 0, 0);   \
        const int ip = ilo + t * 16 + l15;                                     \
        float h0 = a[0] + (float)xv[t][0];                                     \
        float h1 = a[1] + (float)xv[t][1];                                     \
        float h2 = a[2] + (float)xv[t][2];                                     \
        float h3 = a[3] + (float)xv[t][3];                                     \
        if (do_relu) {                                                         \
          h0 = fmaxf(h0, 0.f); h1 = fmaxf(h1, 0.f);                            \
          h2 = fmaxf(h2, 0.f); h3 = fmaxf(h3, 0.f);                            \
        }                                                                      \
        f16x4 hw;                                                              \
        hw[0] = (f16)h0; hw[1] = (f16)h1; hw[2] = (f16)h2; hw[3] = (f16)h3;    \
        const bool ok = (ip <= ihi);                                           \
        if (ok) *(f16x4*)&hp[ip + 1][c0] = hw;                                 \
        psoff[t] = ok ? offv[t] : -1;                                          \
        phw[t] = hw;                                                           \
      }                                                                        \
    }

    switch (ntiles) {
      case 1: DIAG_BODY(1); break;
      case 2: DIAG_BODY(2); break;
      case 3: DIAG_BODY(3); break;
      case 4: DIAG_BODY(4); break;
      default: DIAG_BODY(5); break;
    }
#undef DIAG_BODY

    // tiles not touched this diagonal must not re-flush stale data
#pragma unroll
    for (int t = 0; t < 5; ++t)
      if (t >= ntiles) psoff[t] = -1;

    // rotate prefetch registers
#pragma unroll
    for (int t = 0; t < 5; ++t) { xv[t] = nxv[t]; offv[t] = noffv[t]; }

    __syncthreads();
  }

  // final flush (last diagonal's deferred stores)
#pragma unroll
  for (int t = 0; t < 5; ++t)
    if (psoff[t] >= 0) *(f16x4*)(sbase + psoff[t]) = phw[t];
}

// ---------------------------------------------------------------------------
// Reduce: out[b][c][i][j] = sum over 4 dirs of scratch[dir][b][i][j][c].
// f16x8 loads (16B/lane), fp32 accumulate, LDS [j][c] tile (stride 68),
// float4 global stores. One block per (b, i) = 2560 blocks.
// ---------------------------------------------------------------------------
__global__ __launch_bounds__(256) void reduce_kernel(const f16* __restrict__ s,
                                                     float* __restrict__ out) {
  const int bi = blockIdx.x;            // b*HH + i
  const int b = bi / HH, i = bi - b * HH;
  __shared__ float tile[WW][CC + 4];    // [j][c]
  const size_t dstride = (size_t)BB * SLICE;
  const f16* p = s + (size_t)b * SLICE + (size_t)i * (WW * CC);
  for (int idx = threadIdx.x; idx < (WW * CC) / 8; idx += 256) {  // 640
    const int j = idx >> 3, c8 = (idx & 7) * 8;
    const size_t off = (size_t)j * CC + c8;
    const f16x8 a0 = *(const f16x8*)(p + off);
    const f16x8 a1 = *(const f16x8*)(p + off + dstride);
    const f16x8 a2 = *(const f16x8*)(p + off + 2 * dstride);
    const f16x8 a3 = *(const f16x8*)(p + off + 3 * dstride);
    float r[8];
#pragma unroll
    for (int k = 0; k < 8; ++k)
      r[k] = (float)a0[k] + (float)a1[k] + (float)a2[k] + (float)a3[k];
    *(floatx4*)&tile[j][c8]     = *(const floatx4*)&r[0];  // aligned (272j+...)
    *(floatx4*)&tile[j][c8 + 4] = *(const floatx4*)&r[4];
  }
  __syncthreads();
  float* op = out + ((size_t)(b * CC) * HH + i) * WW;  // + c*(H*W) + j
  for (int idx = threadIdx.x; idx < (CC * WW) / 4; idx += 256) {  // 1280
    const int c = idx / 20, jq = idx - c * 20;
    floatx4 v;
    v[0] = tile[jq * 4 + 0][c];
    v[1] = tile[jq * 4 + 1][c];
    v[2] = tile[jq * 4 + 2][c];
    v[3] = tile[jq * 4 + 3][c];
    *(floatx4*)(op + (size_t)c * (HH * WW) + jq * 4) = v;  // coalesced, aligned
  }
}

// ---------------------------------------------------------------------------
extern "C" void kernel_launch(void* const* d_in, const int* in_sizes, int n_in,
                              void* d_out, int out_size, void* d_ws, size_t ws_size,
                              hipStream_t stream) {
  const float* x = (const float*)d_in[0];
  GPtrs g;
  for (int k = 0; k < 8; ++k) g.p[k] = (const float*)d_in[k + 1];  // g1,g2,g4,g5,g7,g8,g10,g11
  f16* xT = (f16*)d_ws;                         // 26.2 MB
  f16* scratch = xT + (size_t)BB * SLICE;       // 104.9 MB

  xpose_kernel<<<BB * HH, 256, 0, stream>>>(x, xT);
  dag_kernel<<<4 * BB, 256, 0, stream>>>((const f16*)xT, g, scratch);
  reduce_kernel<<<BB * HH, 256, 0, stream>>>((const f16*)scratch, (float*)d_out);
}